// Round 1
// baseline (332.929 us; speedup 1.0000x reference)
//
#include <hip/hip_runtime.h>

// Triline interpolation: out[b,c] = sum over axes of lerp(line[idx0], line[idx0+1], w)
// B=1M, N=512, C=64, fp32 throughout. Memory-bound: 256 MB out writes dominate.
// Layout: 16 threads per point, each owns one float4 (4 channels) -> coalesced
// 256 B/point stores; line gathers are L2-resident (384 KiB total).

typedef float f4 __attribute__((ext_vector_type(4)));

constexpr int kN  = 512;
constexpr int kC4 = 16;   // C/4 = 64/4 float4 chunks per row

__global__ __launch_bounds__(256) void triline_kernel(
    const float* __restrict__ coords,
    const f4* __restrict__ xl,
    const f4* __restrict__ yl,
    const f4* __restrict__ zl,
    const float* __restrict__ grid,
    f4* __restrict__ out,
    int total)
{
    int gid = blockIdx.x * 256 + threadIdx.x;
    if (gid >= total) return;
    int b  = gid >> 4;    // point index
    int c4 = gid & 15;    // which float4 chunk of the 64-channel row

    float g0     = grid[0];
    float inv_dg = 1.0f / (grid[1] - g0);

    float cx = coords[3 * b + 0];
    float cy = coords[3 * b + 1];
    float cz = coords[3 * b + 2];

    float px = (cx - g0) * inv_dg;
    float py = (cy - g0) * inv_dg;
    float pz = (cz - g0) * inv_dg;

    int ix = min(max((int)floorf(px), 0), kN - 2);
    int iy = min(max((int)floorf(py), 0), kN - 2);
    int iz = min(max((int)floorf(pz), 0), kN - 2);

    float wx = px - (float)ix;
    float wy = py - (float)iy;
    float wz = pz - (float)iz;

    f4 x0 = xl[ix * kC4 + c4];
    f4 x1 = xl[ix * kC4 + kC4 + c4];
    f4 y0 = yl[iy * kC4 + c4];
    f4 y1 = yl[iy * kC4 + kC4 + c4];
    f4 z0 = zl[iz * kC4 + c4];
    f4 z1 = zl[iz * kC4 + kC4 + c4];

    f4 r = x0 + (x1 - x0) * wx;
    r    = r + y0 + (y1 - y0) * wy;
    r    = r + z0 + (z1 - z0) * wz;

    // Streaming write: don't pollute L2 (lines must stay resident there).
    __builtin_nontemporal_store(r, &out[gid]);
}

extern "C" void kernel_launch(void* const* d_in, const int* in_sizes, int n_in,
                              void* d_out, int out_size, void* d_ws, size_t ws_size,
                              hipStream_t stream) {
    const float* coords = (const float*)d_in[0];
    const f4*    xl     = (const f4*)d_in[1];
    const f4*    yl     = (const f4*)d_in[2];
    const f4*    zl     = (const f4*)d_in[3];
    const float* grid   = (const float*)d_in[4];
    f4*          out    = (f4*)d_out;

    int B      = in_sizes[0] / 3;   // 1048576
    int total  = B * kC4;           // one thread per float4 chunk
    int blocks = (total + 255) / 256;

    triline_kernel<<<blocks, 256, 0, stream>>>(coords, xl, yl, zl, grid, out, total);
}